// Round 2
// baseline (581.193 us; speedup 1.0000x reference)
//
#include <hip/hip_runtime.h>
#include <hip/hip_bf16.h>

// MoE top-1 (GShard) for MI355X.
// S=8192 tokens, m=1024, E=8, ffn=4096, C=1024.
// R4: T3-minimum double-buffered prefetch in gemm_core (both GEMMs).
//     R3 post-mortem: bank conflicts dropped 4.5x but dur rose — gemm2 is
//     latency-bound at 2 blocks/CU (grid=512), each K-step serially paying
//     full global-load latency at the vmcnt(0) barrier drain. Prefetch gives
//     next-tile loads the ds_read+MFMA window to complete.

#define NTOK 8192
#define DM   1024
#define NE   8
#define NF   4096
#define CAP  1024

typedef __bf16 bf16x8 __attribute__((ext_vector_type(8)));
typedef float  f32x4  __attribute__((ext_vector_type(4)));
typedef unsigned short us8v __attribute__((ext_vector_type(8)));

__device__ __forceinline__ unsigned short f2bf(float f) {
    union { float f; unsigned int u; } v; v.f = f;
    unsigned int u = v.u;
    return (unsigned short)((u + 0x7FFFu + ((u >> 16) & 1u)) >> 16); // RNE
}

__device__ __forceinline__ void async_cp16(const unsigned short* g, unsigned short* l) {
    __builtin_amdgcn_global_load_lds(
        (const __attribute__((address_space(1))) void*)g,
        (__attribute__((address_space(3))) void*)l, 16, 0, 0);
}

// ---------------- gating: one wave per token ----------------
__global__ __launch_bounds__(256) void gate_kernel(
    const float* __restrict__ x, const float* __restrict__ wg,
    int* __restrict__ eid, float* __restrict__ gatev)
{
    int wave = threadIdx.x >> 6;
    int lane = threadIdx.x & 63;
    int t = blockIdx.x * 4 + wave;
    const float4* xr4 = (const float4*)(x + (size_t)t * DM);
    float acc[NE];
#pragma unroll
    for (int e = 0; e < NE; ++e) acc[e] = 0.f;
#pragma unroll
    for (int it = 0; it < 4; ++it) {
        int k4 = lane + it * 64;
        float4 xv = xr4[k4];
        float xc[4] = {xv.x, xv.y, xv.z, xv.w};
#pragma unroll
        for (int c = 0; c < 4; ++c) {
            const float4* wr = (const float4*)(wg + (size_t)(k4 * 4 + c) * NE);
            float4 w0 = wr[0], w1 = wr[1];
            acc[0] += xc[c] * w0.x; acc[1] += xc[c] * w0.y;
            acc[2] += xc[c] * w0.z; acc[3] += xc[c] * w0.w;
            acc[4] += xc[c] * w1.x; acc[5] += xc[c] * w1.y;
            acc[6] += xc[c] * w1.z; acc[7] += xc[c] * w1.w;
        }
    }
#pragma unroll
    for (int off = 32; off >= 1; off >>= 1) {
#pragma unroll
        for (int e = 0; e < NE; ++e) acc[e] += __shfl_xor(acc[e], off, 64);
    }
    if (lane == 0) {
        int best = 0; float bm = acc[0];
#pragma unroll
        for (int e = 1; e < NE; ++e) if (acc[e] > bm) { bm = acc[e]; best = e; } // first-max like jnp.argmax
        float ssum = 0.f;
#pragma unroll
        for (int e = 0; e < NE; ++e) ssum += __expf(acc[e] - bm);
        eid[t] = best;
        gatev[t] = 1.0f / ssum;  // softmax prob of argmax expert
    }
}

// ---------------- ordered per-expert cumsum, wave-shuffle scan ----------------
__global__ __launch_bounds__(1024) void scan_kernel(
    const int* __restrict__ eid, int* __restrict__ slot_token)
{
    __shared__ int wtot[16][NE];
    int tid = threadIdx.x;
    int lane = tid & 63, wv = tid >> 6;
#pragma unroll
    for (int i = 0; i < 8; ++i) slot_token[tid + i * 1024] = -1;

    int el[8];
    int cnt[NE];
#pragma unroll
    for (int e = 0; e < NE; ++e) cnt[e] = 0;
#pragma unroll
    for (int i = 0; i < 8; ++i) {
        int e = eid[tid * 8 + i];
        el[i] = e;
        cnt[e]++;
    }
    int incl[NE];
#pragma unroll
    for (int e = 0; e < NE; ++e) incl[e] = cnt[e];
#pragma unroll
    for (int off = 1; off <= 32; off <<= 1) {
#pragma unroll
        for (int e = 0; e < NE; ++e) {
            int v = __shfl_up(incl[e], off, 64);
            if (lane >= off) incl[e] += v;
        }
    }
    if (lane == 63) {
#pragma unroll
        for (int e = 0; e < NE; ++e) wtot[wv][e] = incl[e];
    }
    __syncthreads();
    int base[NE];
#pragma unroll
    for (int e = 0; e < NE; ++e) {
        int s = 0;
        for (int w = 0; w < 16; ++w) s += (w < wv) ? wtot[w][e] : 0;
        base[e] = s + incl[e] - cnt[e];   // exclusive prefix for this thread
    }
#pragma unroll
    for (int i = 0; i < 8; ++i) {
        int e = el[i];
        int loc = base[e]++;
        if (loc < CAP) slot_token[e * CAP + loc] = tid * 8 + i;
    }
}

// ---------------- f32 [E][K][N] -> bf16 [E][N][K] convert+transpose ----------------
template<int K, int N>
__global__ __launch_bounds__(256) void convT_kernel(
    const float* __restrict__ W, unsigned short* __restrict__ WT)
{
    __shared__ unsigned short tile[64][72];
    int e = blockIdx.z;
    int k0 = blockIdx.y * 64, n0 = blockIdx.x * 64;
    const float* Wp = W + (size_t)e * K * N;
    unsigned short* WTp = WT + (size_t)e * K * N;
    int tid = threadIdx.x;
    int cn = (tid & 15) * 4;
    int rk = tid >> 4;
#pragma unroll
    for (int i = 0; i < 4; ++i) {
        int k = rk + i * 16;
        float4 v = *(const float4*)(Wp + (size_t)(k0 + k) * N + n0 + cn);
        tile[cn + 0][k] = f2bf(v.x);
        tile[cn + 1][k] = f2bf(v.y);
        tile[cn + 2][k] = f2bf(v.z);
        tile[cn + 3][k] = f2bf(v.w);
    }
    __syncthreads();
    int ck = (tid & 7) * 8;
    int rn = tid >> 3;
#pragma unroll
    for (int i = 0; i < 2; ++i) {
        int n = rn + i * 32;
        us8v o;
#pragma unroll
        for (int c = 0; c < 8; ++c) o[c] = tile[n][ck + c];
        *(us8v*)(WTp + (size_t)(n0 + n) * K + k0 + ck) = o;
    }
}

// ---------------- gather dispatched tokens into bf16 [E*C][m] ----------------
__global__ __launch_bounds__(256) void gather_kernel(
    const float* __restrict__ x, const int* __restrict__ slot_token,
    unsigned short* __restrict__ Xd)
{
    int tid = threadIdx.x;
    int local = tid & 127;
    int slot = blockIdx.x * 2 + (tid >> 7);
    int t = slot_token[slot];
    int c = local * 8;
    us8v o;
    if (t >= 0) {
        const float4* p = (const float4*)(x + (size_t)t * DM + c);
        float4 v0 = p[0], v1 = p[1];
        o[0] = f2bf(v0.x); o[1] = f2bf(v0.y); o[2] = f2bf(v0.z); o[3] = f2bf(v0.w);
        o[4] = f2bf(v1.x); o[5] = f2bf(v1.y); o[6] = f2bf(v1.z); o[7] = f2bf(v1.w);
    } else {
#pragma unroll
        for (int c8 = 0; c8 < 8; ++c8) o[c8] = 0;
    }
    *(us8v*)(Xd + (size_t)slot * DM + c) = o;
}

// ---------------- m97-style bf16 GEMM core: 128x128 tile, BK=32,
// ---------------- T3-min double-buffered prefetch (1 barrier / K-step) ------
// As0/Bs0 each point at 2 buffers of 4096 shorts (8KB): buf = base + cur*4096.
template<int K>
__device__ __forceinline__ void gemm_core(
    const unsigned short* __restrict__ Ab, const unsigned short* __restrict__ Bb,
    unsigned short* As0, unsigned short* Bs0, f32x4 acc[4][4])
{
    int tid = threadIdx.x;
    int wave = tid >> 6, lane = tid & 63;
    int wr = (wave >> 1) * 64;
    int wc = (wave & 1) * 64;
#pragma unroll
    for (int i = 0; i < 4; ++i)
#pragma unroll
        for (int j = 0; j < 4; ++j) acc[i][j] = (f32x4){0.f, 0.f, 0.f, 0.f};

    int srow = (lane >> 2);
    int scol = (lane & 3) * 8;

    // prologue: stage tile 0 into buffer 0
#pragma unroll
    for (int i = 0; i < 2; ++i) {
        int q = wave * 2 + i;
        int row = q * 16 + srow;
        async_cp16(Ab + (size_t)row * K + scol, As0 + q * 512);
        async_cp16(Bb + (size_t)row * K + scol, Bs0 + q * 512);
    }
    __syncthreads();   // drains vmcnt(0): tile 0 resident

    int cur = 0;
    for (int kt = 0; kt < K; kt += 32) {
        unsigned short* Asc = As0 + cur * 4096;
        unsigned short* Bsc = Bs0 + cur * 4096;
        // ds_read current tile fragments
        bf16x8 af[4], bfr[4];
#pragma unroll
        for (int i = 0; i < 4; ++i) {
            int r = wr + i * 16 + (lane & 15);
            af[i] = *(const bf16x8*)(Asc + r * 32 + (lane >> 4) * 8);
        }
#pragma unroll
        for (int j = 0; j < 4; ++j) {
            int c = wc + j * 16 + (lane & 15);
            bfr[j] = *(const bf16x8*)(Bsc + c * 32 + (lane >> 4) * 8);
        }
        // issue next-tile stage into the other buffer; it has the whole
        // MFMA cluster to complete before the end-of-iteration drain.
        if (kt + 32 < K) {
            unsigned short* Asn = As0 + (cur ^ 1) * 4096;
            unsigned short* Bsn = Bs0 + (cur ^ 1) * 4096;
#pragma unroll
            for (int i = 0; i < 2; ++i) {
                int q = wave * 2 + i;
                int row = q * 16 + srow;
                async_cp16(Ab + (size_t)row * K + kt + 32 + scol, Asn + q * 512);
                async_cp16(Bb + (size_t)row * K + kt + 32 + scol, Bsn + q * 512);
            }
        }
#pragma unroll
        for (int i = 0; i < 4; ++i)
#pragma unroll
            for (int j = 0; j < 4; ++j)
                acc[i][j] = __builtin_amdgcn_mfma_f32_16x16x32_bf16(af[i], bfr[j], acc[i][j], 0, 0, 0);
        __syncthreads();   // vmcnt(0)+lgkm drain: next tile resident, cur readable by none
        cur ^= 1;
    }
}

// GEMM1: H[e] = relu(Xd[e] @ W1[e]) -> bf16, LDS-transpose epilogue w/ 16B stores.
__global__ __launch_bounds__(256, 2) void gemm1_kernel(
    const unsigned short* __restrict__ Xd, const unsigned short* __restrict__ W1T,
    unsigned short* __restrict__ H)
{
    __shared__ unsigned short smem[16384];  // As dbuf(8K shorts) + Bs dbuf(8K shorts) = 32KB
    unsigned short* As = smem;
    unsigned short* Bs = smem + 8192;
    int e = blockIdx.z;
    const unsigned short* Ab = Xd + ((size_t)e * CAP + blockIdx.y * 128) * DM;
    const unsigned short* Bb = W1T + ((size_t)e * NF + blockIdx.x * 128) * DM;
    f32x4 acc[4][4];
    gemm_core<DM>(Ab, Bb, As, Bs, acc);

    int tid = threadIdx.x, wave = tid >> 6, lane = tid & 63;
    int wc = (wave & 1) * 64;
    size_t Hrow0 = ((size_t)e * CAP + blockIdx.y * 128) * NF + blockIdx.x * 128;
    unsigned short* buf = smem;  // 64 rows x 128 cols bf16 = 16KB (reuses As dbuf)
#pragma unroll
    for (int p = 0; p < 2; ++p) {
        if ((wave >> 1) == p) {
#pragma unroll
            for (int i = 0; i < 4; ++i) {
#pragma unroll
                for (int j = 0; j < 4; ++j) {
                    int col = wc + j * 16 + (lane & 15);
#pragma unroll
                    for (int f = 0; f < 4; ++f) {
                        int lr = i * 16 + (lane >> 4) * 4 + f;
                        float v = acc[i][j][f];
                        v = v > 0.f ? v : 0.f;
                        buf[lr * 128 + col] = f2bf(v);
                    }
                }
            }
        }
        __syncthreads();
#pragma unroll
        for (int v = 0; v < 4; ++v) {
            int sidx = tid + v * 256;
            int r = sidx >> 4, seg = sidx & 15;
            us8v o = *(const us8v*)(buf + r * 128 + seg * 8);
            *(us8v*)(H + Hrow0 + (size_t)(p * 64 + r) * NF + seg * 8) = o;
        }
        __syncthreads();
    }
}

// GEMM2: EO[e] = H[e] @ W2[e]; 128x128/BK=32 prefetch core, gate-scale + scatter.
__global__ __launch_bounds__(256, 2) void gemm2_kernel(
    const unsigned short* __restrict__ H, const unsigned short* __restrict__ W2T,
    const int* __restrict__ slot_token, const float* __restrict__ gatev,
    float* __restrict__ out)
{
    __shared__ unsigned short smem[16384];  // As dbuf + Bs dbuf = 32KB
    unsigned short* As = smem;
    unsigned short* Bs = smem + 8192;
    int e = blockIdx.z;
    const unsigned short* Ab = H + ((size_t)e * CAP + blockIdx.y * 128) * NF;
    const unsigned short* Bb = W2T + ((size_t)e * DM + blockIdx.x * 128) * NF;
    f32x4 acc[4][4];
    gemm_core<NF>(Ab, Bb, As, Bs, acc);

    int tid = threadIdx.x, wave = tid >> 6, lane = tid & 63;
    int wr = (wave >> 1) * 64;
    int wc = (wave & 1) * 64;
    int slot0 = e * CAP + blockIdx.y * 128;
    int colbase = blockIdx.x * 128 + wc + (lane & 15);
#pragma unroll
    for (int i = 0; i < 4; ++i) {
        int rbase = wr + i * 16 + (lane >> 4) * 4;
#pragma unroll
        for (int f = 0; f < 4; ++f) {
            int row = rbase + f;
            int t = slot_token[slot0 + row];
            if (t >= 0) {
                float g = gatev[t];
#pragma unroll
                for (int j = 0; j < 4; ++j) {
                    out[(size_t)t * DM + colbase + j * 16] = acc[i][j][f] * g;
                }
            }
        }
    }
}

extern "C" void kernel_launch(void* const* d_in, const int* in_sizes, int n_in,
                              void* d_out, int out_size, void* d_ws, size_t ws_size,
                              hipStream_t stream)
{
    const float* x  = (const float*)d_in[0];
    const float* wg = (const float*)d_in[1];
    const float* w1 = (const float*)d_in[2];
    const float* w2 = (const float*)d_in[3];
    float* out = (float*)d_out;

    char* ws = (char*)d_ws;
    size_t o = 0;
    auto nxt = [&](size_t b) { size_t r = o; o += (b + 255) & ~(size_t)255; return r; };
    int*   eid        = (int*)  (ws + nxt((size_t)NTOK * 4));
    float* gatev      = (float*)(ws + nxt((size_t)NTOK * 4));
    int*   slot_token = (int*)  (ws + nxt((size_t)NTOK * 4));
    unsigned short* Xd = (unsigned short*)(ws + nxt((size_t)NTOK * DM * 2));
    unsigned short* WT = (unsigned short*)(ws + nxt((size_t)NE * NF * DM * 2)); // W1T then W2T (aliased)
    unsigned short* Hb = (unsigned short*)(ws + nxt((size_t)NE * CAP * NF * 2));

    gate_kernel<<<NTOK / 4, 256, 0, stream>>>(x, wg, eid, gatev);
    scan_kernel<<<1, 1024, 0, stream>>>(eid, slot_token);
    convT_kernel<DM, NF><<<dim3(NF / 64, DM / 64, NE), 256, 0, stream>>>(w1, WT);
    gather_kernel<<<NTOK / 2, 256, 0, stream>>>(x, slot_token, Xd);
    gemm1_kernel<<<dim3(NF / 128, CAP / 128, NE), 256, 0, stream>>>(Xd, WT, Hb);
    convT_kernel<NF, DM><<<dim3(DM / 64, NF / 64, NE), 256, 0, stream>>>(w2, WT);
    hipMemsetAsync(d_out, 0, (size_t)out_size * sizeof(float), stream);
    gemm2_kernel<<<dim3(DM / 128, CAP / 128, NE), 256, 0, stream>>>(Hb, WT, slot_token, gatev, out);
}

// Round 3
// 566.743 us; speedup vs baseline: 1.0255x; 1.0255x over previous
//
#include <hip/hip_runtime.h>
#include <hip/hip_bf16.h>

// MoE top-1 (GShard) for MI355X.
// S=8192 tokens, m=1024, E=8, ffn=4096, C=1024.
// R5: gemm2 = bank-clean 128x128/BK=32 core (R3) + split-K x2 (grid 512->1024,
//     2->4 blocks/CU) with unsafeAtomicAdd f32 epilogue (2 commutative adds =
//     deterministic). R4's dbuf reverted everywhere: __syncthreads drains
//     vmcnt(0) so source-level prefetch cannot beat the barrier drain (m99/m100);
//     TLP via grid is what hides it (m97: 3 blocks/CU).

#define NTOK 8192
#define DM   1024
#define NE   8
#define NF   4096
#define CAP  1024

typedef __bf16 bf16x8 __attribute__((ext_vector_type(8)));
typedef float  f32x4  __attribute__((ext_vector_type(4)));
typedef unsigned short us8v __attribute__((ext_vector_type(8)));

__device__ __forceinline__ unsigned short f2bf(float f) {
    union { float f; unsigned int u; } v; v.f = f;
    unsigned int u = v.u;
    return (unsigned short)((u + 0x7FFFu + ((u >> 16) & 1u)) >> 16); // RNE
}

__device__ __forceinline__ void async_cp16(const unsigned short* g, unsigned short* l) {
    __builtin_amdgcn_global_load_lds(
        (const __attribute__((address_space(1))) void*)g,
        (__attribute__((address_space(3))) void*)l, 16, 0, 0);
}

// ---------------- gating: one wave per token ----------------
__global__ __launch_bounds__(256) void gate_kernel(
    const float* __restrict__ x, const float* __restrict__ wg,
    int* __restrict__ eid, float* __restrict__ gatev)
{
    int wave = threadIdx.x >> 6;
    int lane = threadIdx.x & 63;
    int t = blockIdx.x * 4 + wave;
    const float4* xr4 = (const float4*)(x + (size_t)t * DM);
    float acc[NE];
#pragma unroll
    for (int e = 0; e < NE; ++e) acc[e] = 0.f;
#pragma unroll
    for (int it = 0; it < 4; ++it) {
        int k4 = lane + it * 64;
        float4 xv = xr4[k4];
        float xc[4] = {xv.x, xv.y, xv.z, xv.w};
#pragma unroll
        for (int c = 0; c < 4; ++c) {
            const float4* wr = (const float4*)(wg + (size_t)(k4 * 4 + c) * NE);
            float4 w0 = wr[0], w1 = wr[1];
            acc[0] += xc[c] * w0.x; acc[1] += xc[c] * w0.y;
            acc[2] += xc[c] * w0.z; acc[3] += xc[c] * w0.w;
            acc[4] += xc[c] * w1.x; acc[5] += xc[c] * w1.y;
            acc[6] += xc[c] * w1.z; acc[7] += xc[c] * w1.w;
        }
    }
#pragma unroll
    for (int off = 32; off >= 1; off >>= 1) {
#pragma unroll
        for (int e = 0; e < NE; ++e) acc[e] += __shfl_xor(acc[e], off, 64);
    }
    if (lane == 0) {
        int best = 0; float bm = acc[0];
#pragma unroll
        for (int e = 1; e < NE; ++e) if (acc[e] > bm) { bm = acc[e]; best = e; } // first-max like jnp.argmax
        float ssum = 0.f;
#pragma unroll
        for (int e = 0; e < NE; ++e) ssum += __expf(acc[e] - bm);
        eid[t] = best;
        gatev[t] = 1.0f / ssum;  // softmax prob of argmax expert
    }
}

// ---------------- ordered per-expert cumsum, wave-shuffle scan ----------------
__global__ __launch_bounds__(1024) void scan_kernel(
    const int* __restrict__ eid, int* __restrict__ slot_token)
{
    __shared__ int wtot[16][NE];
    int tid = threadIdx.x;
    int lane = tid & 63, wv = tid >> 6;
#pragma unroll
    for (int i = 0; i < 8; ++i) slot_token[tid + i * 1024] = -1;

    int el[8];
    int cnt[NE];
#pragma unroll
    for (int e = 0; e < NE; ++e) cnt[e] = 0;
#pragma unroll
    for (int i = 0; i < 8; ++i) {
        int e = eid[tid * 8 + i];
        el[i] = e;
        cnt[e]++;
    }
    int incl[NE];
#pragma unroll
    for (int e = 0; e < NE; ++e) incl[e] = cnt[e];
#pragma unroll
    for (int off = 1; off <= 32; off <<= 1) {
#pragma unroll
        for (int e = 0; e < NE; ++e) {
            int v = __shfl_up(incl[e], off, 64);
            if (lane >= off) incl[e] += v;
        }
    }
    if (lane == 63) {
#pragma unroll
        for (int e = 0; e < NE; ++e) wtot[wv][e] = incl[e];
    }
    __syncthreads();
    int base[NE];
#pragma unroll
    for (int e = 0; e < NE; ++e) {
        int s = 0;
        for (int w = 0; w < 16; ++w) s += (w < wv) ? wtot[w][e] : 0;
        base[e] = s + incl[e] - cnt[e];   // exclusive prefix for this thread
    }
#pragma unroll
    for (int i = 0; i < 8; ++i) {
        int e = el[i];
        int loc = base[e]++;
        if (loc < CAP) slot_token[e * CAP + loc] = tid * 8 + i;
    }
}

// ---------------- f32 [E][K][N] -> bf16 [E][N][K] convert+transpose ----------------
template<int K, int N>
__global__ __launch_bounds__(256) void convT_kernel(
    const float* __restrict__ W, unsigned short* __restrict__ WT)
{
    __shared__ unsigned short tile[64][72];
    int e = blockIdx.z;
    int k0 = blockIdx.y * 64, n0 = blockIdx.x * 64;
    const float* Wp = W + (size_t)e * K * N;
    unsigned short* WTp = WT + (size_t)e * K * N;
    int tid = threadIdx.x;
    int cn = (tid & 15) * 4;
    int rk = tid >> 4;
#pragma unroll
    for (int i = 0; i < 4; ++i) {
        int k = rk + i * 16;
        float4 v = *(const float4*)(Wp + (size_t)(k0 + k) * N + n0 + cn);
        tile[cn + 0][k] = f2bf(v.x);
        tile[cn + 1][k] = f2bf(v.y);
        tile[cn + 2][k] = f2bf(v.z);
        tile[cn + 3][k] = f2bf(v.w);
    }
    __syncthreads();
    int ck = (tid & 7) * 8;
    int rn = tid >> 3;
#pragma unroll
    for (int i = 0; i < 2; ++i) {
        int n = rn + i * 32;
        us8v o;
#pragma unroll
        for (int c = 0; c < 8; ++c) o[c] = tile[n][ck + c];
        *(us8v*)(WTp + (size_t)(n0 + n) * K + k0 + ck) = o;
    }
}

// ---------------- gather dispatched tokens into bf16 [E*C][m] ----------------
__global__ __launch_bounds__(256) void gather_kernel(
    const float* __restrict__ x, const int* __restrict__ slot_token,
    unsigned short* __restrict__ Xd)
{
    int tid = threadIdx.x;
    int local = tid & 127;
    int slot = blockIdx.x * 2 + (tid >> 7);
    int t = slot_token[slot];
    int c = local * 8;
    us8v o;
    if (t >= 0) {
        const float4* p = (const float4*)(x + (size_t)t * DM + c);
        float4 v0 = p[0], v1 = p[1];
        o[0] = f2bf(v0.x); o[1] = f2bf(v0.y); o[2] = f2bf(v0.z); o[3] = f2bf(v0.w);
        o[4] = f2bf(v1.x); o[5] = f2bf(v1.y); o[6] = f2bf(v1.z); o[7] = f2bf(v1.w);
    } else {
#pragma unroll
        for (int c8 = 0; c8 < 8; ++c8) o[c8] = 0;
    }
    *(us8v*)(Xd + (size_t)slot * DM + c) = o;
}

// ---------------- m97-style bf16 GEMM core: 128x128 tile, BK=32 ----------------
// KLEN = k-extent this block sums over; LD = row stride of A/B panels.
template<int KLEN, int LD>
__device__ __forceinline__ void gemm_core(
    const unsigned short* __restrict__ Ab, const unsigned short* __restrict__ Bb,
    unsigned short* As, unsigned short* Bs, f32x4 acc[4][4])
{
    int tid = threadIdx.x;
    int wave = tid >> 6, lane = tid & 63;
    int wr = (wave >> 1) * 64;
    int wc = (wave & 1) * 64;
#pragma unroll
    for (int i = 0; i < 4; ++i)
#pragma unroll
        for (int j = 0; j < 4; ++j) acc[i][j] = (f32x4){0.f, 0.f, 0.f, 0.f};

    int srow = (lane >> 2);
    int scol = (lane & 3) * 8;

    for (int kt = 0; kt < KLEN; kt += 32) {
#pragma unroll
        for (int i = 0; i < 2; ++i) {
            int q = wave * 2 + i;
            int row = q * 16 + srow;
            async_cp16(Ab + (size_t)row * LD + kt + scol, As + q * 512);
            async_cp16(Bb + (size_t)row * LD + kt + scol, Bs + q * 512);
        }
        __syncthreads();
        bf16x8 af[4], bfr[4];
#pragma unroll
        for (int i = 0; i < 4; ++i) {
            int r = wr + i * 16 + (lane & 15);
            af[i] = *(const bf16x8*)(As + r * 32 + (lane >> 4) * 8);
        }
#pragma unroll
        for (int j = 0; j < 4; ++j) {
            int c = wc + j * 16 + (lane & 15);
            bfr[j] = *(const bf16x8*)(Bs + c * 32 + (lane >> 4) * 8);
        }
#pragma unroll
        for (int i = 0; i < 4; ++i)
#pragma unroll
            for (int j = 0; j < 4; ++j)
                acc[i][j] = __builtin_amdgcn_mfma_f32_16x16x32_bf16(af[i], bfr[j], acc[i][j], 0, 0, 0);
        __syncthreads();
    }
}

// GEMM1: H[e] = relu(Xd[e] @ W1[e]) -> bf16, LDS-transpose epilogue w/ 16B stores.
__global__ __launch_bounds__(256, 2) void gemm1_kernel(
    const unsigned short* __restrict__ Xd, const unsigned short* __restrict__ W1T,
    unsigned short* __restrict__ H)
{
    __shared__ unsigned short smem[8192];   // As(4096) + Bs(4096); reused as epilogue buf
    unsigned short* As = smem;
    unsigned short* Bs = smem + 4096;
    int e = blockIdx.z;
    const unsigned short* Ab = Xd + ((size_t)e * CAP + blockIdx.y * 128) * DM;
    const unsigned short* Bb = W1T + ((size_t)e * NF + blockIdx.x * 128) * DM;
    f32x4 acc[4][4];
    gemm_core<DM, DM>(Ab, Bb, As, Bs, acc);

    int tid = threadIdx.x, wave = tid >> 6, lane = tid & 63;
    int wc = (wave & 1) * 64;
    size_t Hrow0 = ((size_t)e * CAP + blockIdx.y * 128) * NF + blockIdx.x * 128;
    unsigned short* buf = smem;  // 64 rows x 128 cols bf16 = 16KB
#pragma unroll
    for (int p = 0; p < 2; ++p) {
        if ((wave >> 1) == p) {
#pragma unroll
            for (int i = 0; i < 4; ++i) {
#pragma unroll
                for (int j = 0; j < 4; ++j) {
                    int col = wc + j * 16 + (lane & 15);
#pragma unroll
                    for (int f = 0; f < 4; ++f) {
                        int lr = i * 16 + (lane >> 4) * 4 + f;
                        float v = acc[i][j][f];
                        v = v > 0.f ? v : 0.f;
                        buf[lr * 128 + col] = f2bf(v);
                    }
                }
            }
        }
        __syncthreads();
#pragma unroll
        for (int v = 0; v < 4; ++v) {
            int sidx = tid + v * 256;
            int r = sidx >> 4, seg = sidx & 15;
            us8v o = *(const us8v*)(buf + r * 128 + seg * 8);
            *(us8v*)(H + Hrow0 + (size_t)(p * 64 + r) * NF + seg * 8) = o;
        }
        __syncthreads();
    }
}

// GEMM2: EO[e] = H[e] @ W2[e]; 128x128/BK=32 core, split-K x2,
// gate-scale + scatter via HW f32 atomics (2 commutative adds -> deterministic).
__global__ __launch_bounds__(256, 4) void gemm2_kernel(
    const unsigned short* __restrict__ H, const unsigned short* __restrict__ W2T,
    const int* __restrict__ slot_token, const float* __restrict__ gatev,
    float* __restrict__ out)
{
    __shared__ unsigned short smem[8192];   // As(4096) + Bs(4096) = 16KB
    unsigned short* As = smem;
    unsigned short* Bs = smem + 4096;
    int e = blockIdx.z;
    int nb = blockIdx.x >> 1;       // n-tile (DM/128 = 8)
    int ks = blockIdx.x & 1;        // k-half
    const unsigned short* Ab = H + ((size_t)e * CAP + blockIdx.y * 128) * NF + ks * (NF / 2);
    const unsigned short* Bb = W2T + ((size_t)e * DM + nb * 128) * NF + ks * (NF / 2);
    f32x4 acc[4][4];
    gemm_core<NF / 2, NF>(Ab, Bb, As, Bs, acc);

    int tid = threadIdx.x, wave = tid >> 6, lane = tid & 63;
    int wr = (wave >> 1) * 64;
    int wc = (wave & 1) * 64;
    int slot0 = e * CAP + blockIdx.y * 128;
    int colbase = nb * 128 + wc + (lane & 15);
#pragma unroll
    for (int i = 0; i < 4; ++i) {
        int rbase = wr + i * 16 + (lane >> 4) * 4;
#pragma unroll
        for (int f = 0; f < 4; ++f) {
            int row = rbase + f;
            int t = slot_token[slot0 + row];
            if (t >= 0) {
                float g = gatev[t];
#pragma unroll
                for (int j = 0; j < 4; ++j) {
                    unsafeAtomicAdd(&out[(size_t)t * DM + colbase + j * 16], acc[i][j][f] * g);
                }
            }
        }
    }
}

extern "C" void kernel_launch(void* const* d_in, const int* in_sizes, int n_in,
                              void* d_out, int out_size, void* d_ws, size_t ws_size,
                              hipStream_t stream)
{
    const float* x  = (const float*)d_in[0];
    const float* wg = (const float*)d_in[1];
    const float* w1 = (const float*)d_in[2];
    const float* w2 = (const float*)d_in[3];
    float* out = (float*)d_out;

    char* ws = (char*)d_ws;
    size_t o = 0;
    auto nxt = [&](size_t b) { size_t r = o; o += (b + 255) & ~(size_t)255; return r; };
    int*   eid        = (int*)  (ws + nxt((size_t)NTOK * 4));
    float* gatev      = (float*)(ws + nxt((size_t)NTOK * 4));
    int*   slot_token = (int*)  (ws + nxt((size_t)NTOK * 4));
    unsigned short* Xd = (unsigned short*)(ws + nxt((size_t)NTOK * DM * 2));
    unsigned short* WT = (unsigned short*)(ws + nxt((size_t)NE * NF * DM * 2)); // W1T then W2T (aliased)
    unsigned short* Hb = (unsigned short*)(ws + nxt((size_t)NE * CAP * NF * 2));

    gate_kernel<<<NTOK / 4, 256, 0, stream>>>(x, wg, eid, gatev);
    scan_kernel<<<1, 1024, 0, stream>>>(eid, slot_token);
    convT_kernel<DM, NF><<<dim3(NF / 64, DM / 64, NE), 256, 0, stream>>>(w1, WT);
    gather_kernel<<<NTOK / 2, 256, 0, stream>>>(x, slot_token, Xd);
    gemm1_kernel<<<dim3(NF / 128, CAP / 128, NE), 256, 0, stream>>>(Xd, WT, Hb);
    convT_kernel<NF, DM><<<dim3(DM / 64, NF / 64, NE), 256, 0, stream>>>(w2, WT);
    hipMemsetAsync(d_out, 0, (size_t)out_size * sizeof(float), stream);
    gemm2_kernel<<<dim3((DM / 128) * 2, CAP / 128, NE), 256, 0, stream>>>(Hb, WT, slot_token, gatev, out);
}

// Round 4
// 563.647 us; speedup vs baseline: 1.0311x; 1.0055x over previous
//
#include <hip/hip_runtime.h>
#include <hip/hip_bf16.h>

// MoE top-1 (GShard) for MI355X.
// S=8192 tokens, m=1024, E=8, ffn=4096, C=1024.
// R6: T3-minimum 2-phase gemm_core: ONE raw s_barrier per K-step, order
//     {STAGE(next) -> ds_read(cur) -> lgkmcnt(0)+sched_barrier -> MFMA ->
//      vmcnt(0) -> s_barrier}. R2-R5 triangulated the plateau (~1300cyc/K-step,
//     MfmaUtil 20 regardless of occupancy/banks) to the __syncthreads vmcnt(0)
//     drain issued right after the stage loads. Depth-1 prefetch + counted
//     placement gives the loads the read+MFMA window. Split-K x2 + atomic
//     epilogue kept (R5: harmless, occupancy 40%).

#define NTOK 8192
#define DM   1024
#define NE   8
#define NF   4096
#define CAP  1024

typedef __bf16 bf16x8 __attribute__((ext_vector_type(8)));
typedef float  f32x4  __attribute__((ext_vector_type(4)));
typedef unsigned short us8v __attribute__((ext_vector_type(8)));

__device__ __forceinline__ unsigned short f2bf(float f) {
    union { float f; unsigned int u; } v; v.f = f;
    unsigned int u = v.u;
    return (unsigned short)((u + 0x7FFFu + ((u >> 16) & 1u)) >> 16); // RNE
}

__device__ __forceinline__ void async_cp16(const unsigned short* g, unsigned short* l) {
    __builtin_amdgcn_global_load_lds(
        (const __attribute__((address_space(1))) void*)g,
        (__attribute__((address_space(3))) void*)l, 16, 0, 0);
}

// ---------------- gating: one wave per token ----------------
__global__ __launch_bounds__(256) void gate_kernel(
    const float* __restrict__ x, const float* __restrict__ wg,
    int* __restrict__ eid, float* __restrict__ gatev)
{
    int wave = threadIdx.x >> 6;
    int lane = threadIdx.x & 63;
    int t = blockIdx.x * 4 + wave;
    const float4* xr4 = (const float4*)(x + (size_t)t * DM);
    float acc[NE];
#pragma unroll
    for (int e = 0; e < NE; ++e) acc[e] = 0.f;
#pragma unroll
    for (int it = 0; it < 4; ++it) {
        int k4 = lane + it * 64;
        float4 xv = xr4[k4];
        float xc[4] = {xv.x, xv.y, xv.z, xv.w};
#pragma unroll
        for (int c = 0; c < 4; ++c) {
            const float4* wr = (const float4*)(wg + (size_t)(k4 * 4 + c) * NE);
            float4 w0 = wr[0], w1 = wr[1];
            acc[0] += xc[c] * w0.x; acc[1] += xc[c] * w0.y;
            acc[2] += xc[c] * w0.z; acc[3] += xc[c] * w0.w;
            acc[4] += xc[c] * w1.x; acc[5] += xc[c] * w1.y;
            acc[6] += xc[c] * w1.z; acc[7] += xc[c] * w1.w;
        }
    }
#pragma unroll
    for (int off = 32; off >= 1; off >>= 1) {
#pragma unroll
        for (int e = 0; e < NE; ++e) acc[e] += __shfl_xor(acc[e], off, 64);
    }
    if (lane == 0) {
        int best = 0; float bm = acc[0];
#pragma unroll
        for (int e = 1; e < NE; ++e) if (acc[e] > bm) { bm = acc[e]; best = e; } // first-max like jnp.argmax
        float ssum = 0.f;
#pragma unroll
        for (int e = 0; e < NE; ++e) ssum += __expf(acc[e] - bm);
        eid[t] = best;
        gatev[t] = 1.0f / ssum;  // softmax prob of argmax expert
    }
}

// ---------------- ordered per-expert cumsum, wave-shuffle scan ----------------
__global__ __launch_bounds__(1024) void scan_kernel(
    const int* __restrict__ eid, int* __restrict__ slot_token)
{
    __shared__ int wtot[16][NE];
    int tid = threadIdx.x;
    int lane = tid & 63, wv = tid >> 6;
#pragma unroll
    for (int i = 0; i < 8; ++i) slot_token[tid + i * 1024] = -1;

    int el[8];
    int cnt[NE];
#pragma unroll
    for (int e = 0; e < NE; ++e) cnt[e] = 0;
#pragma unroll
    for (int i = 0; i < 8; ++i) {
        int e = eid[tid * 8 + i];
        el[i] = e;
        cnt[e]++;
    }
    int incl[NE];
#pragma unroll
    for (int e = 0; e < NE; ++e) incl[e] = cnt[e];
#pragma unroll
    for (int off = 1; off <= 32; off <<= 1) {
#pragma unroll
        for (int e = 0; e < NE; ++e) {
            int v = __shfl_up(incl[e], off, 64);
            if (lane >= off) incl[e] += v;
        }
    }
    if (lane == 63) {
#pragma unroll
        for (int e = 0; e < NE; ++e) wtot[wv][e] = incl[e];
    }
    __syncthreads();
    int base[NE];
#pragma unroll
    for (int e = 0; e < NE; ++e) {
        int s = 0;
        for (int w = 0; w < 16; ++w) s += (w < wv) ? wtot[w][e] : 0;
        base[e] = s + incl[e] - cnt[e];   // exclusive prefix for this thread
    }
#pragma unroll
    for (int i = 0; i < 8; ++i) {
        int e = el[i];
        int loc = base[e]++;
        if (loc < CAP) slot_token[e * CAP + loc] = tid * 8 + i;
    }
}

// ---------------- f32 [E][K][N] -> bf16 [E][N][K] convert+transpose ----------------
template<int K, int N>
__global__ __launch_bounds__(256) void convT_kernel(
    const float* __restrict__ W, unsigned short* __restrict__ WT)
{
    __shared__ unsigned short tile[64][72];
    int e = blockIdx.z;
    int k0 = blockIdx.y * 64, n0 = blockIdx.x * 64;
    const float* Wp = W + (size_t)e * K * N;
    unsigned short* WTp = WT + (size_t)e * K * N;
    int tid = threadIdx.x;
    int cn = (tid & 15) * 4;
    int rk = tid >> 4;
#pragma unroll
    for (int i = 0; i < 4; ++i) {
        int k = rk + i * 16;
        float4 v = *(const float4*)(Wp + (size_t)(k0 + k) * N + n0 + cn);
        tile[cn + 0][k] = f2bf(v.x);
        tile[cn + 1][k] = f2bf(v.y);
        tile[cn + 2][k] = f2bf(v.z);
        tile[cn + 3][k] = f2bf(v.w);
    }
    __syncthreads();
    int ck = (tid & 7) * 8;
    int rn = tid >> 3;
#pragma unroll
    for (int i = 0; i < 2; ++i) {
        int n = rn + i * 32;
        us8v o;
#pragma unroll
        for (int c = 0; c < 8; ++c) o[c] = tile[n][ck + c];
        *(us8v*)(WTp + (size_t)(n0 + n) * K + k0 + ck) = o;
    }
}

// ---------------- gather dispatched tokens into bf16 [E*C][m] ----------------
__global__ __launch_bounds__(256) void gather_kernel(
    const float* __restrict__ x, const int* __restrict__ slot_token,
    unsigned short* __restrict__ Xd)
{
    int tid = threadIdx.x;
    int local = tid & 127;
    int slot = blockIdx.x * 2 + (tid >> 7);
    int t = slot_token[slot];
    int c = local * 8;
    us8v o;
    if (t >= 0) {
        const float4* p = (const float4*)(x + (size_t)t * DM + c);
        float4 v0 = p[0], v1 = p[1];
        o[0] = f2bf(v0.x); o[1] = f2bf(v0.y); o[2] = f2bf(v0.z); o[3] = f2bf(v0.w);
        o[4] = f2bf(v1.x); o[5] = f2bf(v1.y); o[6] = f2bf(v1.z); o[7] = f2bf(v1.w);
    } else {
#pragma unroll
        for (int c8 = 0; c8 < 8; ++c8) o[c8] = 0;
    }
    *(us8v*)(Xd + (size_t)slot * DM + c) = o;
}

// ---------------- bf16 GEMM core: 128x128 tile, BK=32, 2-phase single-barrier --
// KLEN = k-extent this block sums over; LD = row stride of A/B panels.
// As0/Bs0 each point at 2 buffers of 4096 shorts: buf = base + cur*4096.
// Schedule per K-step: STAGE(next) | ds_read(cur) | lgkmcnt(0) | MFMA |
//                      vmcnt(0) | s_barrier.   (T3-minimum, one barrier/step)
template<int KLEN, int LD>
__device__ __forceinline__ void gemm_core(
    const unsigned short* __restrict__ Ab, const unsigned short* __restrict__ Bb,
    unsigned short* As0, unsigned short* Bs0, f32x4 acc[4][4])
{
    int tid = threadIdx.x;
    int wave = tid >> 6, lane = tid & 63;
    int wr = (wave >> 1) * 64;
    int wc = (wave & 1) * 64;
#pragma unroll
    for (int i = 0; i < 4; ++i)
#pragma unroll
        for (int j = 0; j < 4; ++j) acc[i][j] = (f32x4){0.f, 0.f, 0.f, 0.f};

    int srow = (lane >> 2);
    int scol = (lane & 3) * 8;

    // prologue: stage tile 0 into buffer 0, drain, barrier
#pragma unroll
    for (int i = 0; i < 2; ++i) {
        int q = wave * 2 + i;
        int row = q * 16 + srow;
        async_cp16(Ab + (size_t)row * LD + scol, As0 + q * 512);
        async_cp16(Bb + (size_t)row * LD + scol, Bs0 + q * 512);
    }
    asm volatile("s_waitcnt vmcnt(0)" ::: "memory");
    __builtin_amdgcn_s_barrier();

    int cur = 0;
    for (int kt = 0; kt < KLEN; kt += 32) {
        // phase A: issue next-tile stage into the alternate buffer FIRST —
        // these loads have the whole ds_read-wait + MFMA window to land.
        if (kt + 32 < KLEN) {
            unsigned short* Asn = As0 + (cur ^ 1) * 4096;
            unsigned short* Bsn = Bs0 + (cur ^ 1) * 4096;
#pragma unroll
            for (int i = 0; i < 2; ++i) {
                int q = wave * 2 + i;
                int row = q * 16 + srow;
                async_cp16(Ab + (size_t)row * LD + kt + 32 + scol, Asn + q * 512);
                async_cp16(Bb + (size_t)row * LD + kt + 32 + scol, Bsn + q * 512);
            }
        }
        // phase B: ds_read current-tile fragments
        const unsigned short* Asc = As0 + cur * 4096;
        const unsigned short* Bsc = Bs0 + cur * 4096;
        bf16x8 af[4], bfr[4];
#pragma unroll
        for (int i = 0; i < 4; ++i) {
            int r = wr + i * 16 + (lane & 15);
            af[i] = *(const bf16x8*)(Asc + r * 32 + (lane >> 4) * 8);
        }
#pragma unroll
        for (int j = 0; j < 4; ++j) {
            int c = wc + j * 16 + (lane & 15);
            bfr[j] = *(const bf16x8*)(Bsc + c * 32 + (lane >> 4) * 8);
        }
        // all reads of buf[cur] complete before this wave hits the barrier;
        // sched_barrier keeps MFMA from hoisting above the wait (rule #18).
        asm volatile("s_waitcnt lgkmcnt(0)" ::: "memory");
        __builtin_amdgcn_sched_barrier(0);
        // phase C: MFMA cluster
#pragma unroll
        for (int i = 0; i < 4; ++i)
#pragma unroll
            for (int j = 0; j < 4; ++j)
                acc[i][j] = __builtin_amdgcn_mfma_f32_16x16x32_bf16(af[i], bfr[j], acc[i][j], 0, 0, 0);
        // phase D: staged tile landed? then ONE barrier per K-step.
        __builtin_amdgcn_sched_barrier(0);
        asm volatile("s_waitcnt vmcnt(0)" ::: "memory");
        __builtin_amdgcn_s_barrier();
        cur ^= 1;
    }
}

// GEMM1: H[e] = relu(Xd[e] @ W1[e]) -> bf16, LDS-transpose epilogue w/ 16B stores.
__global__ __launch_bounds__(256, 2) void gemm1_kernel(
    const unsigned short* __restrict__ Xd, const unsigned short* __restrict__ W1T,
    unsigned short* __restrict__ H)
{
    __shared__ unsigned short smem[16384];  // As dbuf(8192) + Bs dbuf(8192) = 32KB
    unsigned short* As = smem;
    unsigned short* Bs = smem + 8192;
    int e = blockIdx.z;
    const unsigned short* Ab = Xd + ((size_t)e * CAP + blockIdx.y * 128) * DM;
    const unsigned short* Bb = W1T + ((size_t)e * NF + blockIdx.x * 128) * DM;
    f32x4 acc[4][4];
    gemm_core<DM, DM>(Ab, Bb, As, Bs, acc);
    // gemm_core ends with lgkmcnt(0)+s_barrier: all LDS reads done, safe to reuse.

    int tid = threadIdx.x, wave = tid >> 6, lane = tid & 63;
    int wc = (wave & 1) * 64;
    size_t Hrow0 = ((size_t)e * CAP + blockIdx.y * 128) * NF + blockIdx.x * 128;
    unsigned short* buf = smem;  // 64 rows x 128 cols bf16 = 16KB
#pragma unroll
    for (int p = 0; p < 2; ++p) {
        if ((wave >> 1) == p) {
#pragma unroll
            for (int i = 0; i < 4; ++i) {
#pragma unroll
                for (int j = 0; j < 4; ++j) {
                    int col = wc + j * 16 + (lane & 15);
#pragma unroll
                    for (int f = 0; f < 4; ++f) {
                        int lr = i * 16 + (lane >> 4) * 4 + f;
                        float v = acc[i][j][f];
                        v = v > 0.f ? v : 0.f;
                        buf[lr * 128 + col] = f2bf(v);
                    }
                }
            }
        }
        __syncthreads();
#pragma unroll
        for (int v = 0; v < 4; ++v) {
            int sidx = tid + v * 256;
            int r = sidx >> 4, seg = sidx & 15;
            us8v o = *(const us8v*)(buf + r * 128 + seg * 8);
            *(us8v*)(H + Hrow0 + (size_t)(p * 64 + r) * NF + seg * 8) = o;
        }
        __syncthreads();
    }
}

// GEMM2: EO[e] = H[e] @ W2[e]; 2-phase core, split-K x2,
// gate-scale + scatter via HW f32 atomics (2 commutative adds -> deterministic).
__global__ __launch_bounds__(256, 4) void gemm2_kernel(
    const unsigned short* __restrict__ H, const unsigned short* __restrict__ W2T,
    const int* __restrict__ slot_token, const float* __restrict__ gatev,
    float* __restrict__ out)
{
    __shared__ unsigned short smem[16384];  // As dbuf + Bs dbuf = 32KB
    unsigned short* As = smem;
    unsigned short* Bs = smem + 8192;
    int e = blockIdx.z;
    int nb = blockIdx.x >> 1;       // n-tile (DM/128 = 8)
    int ks = blockIdx.x & 1;        // k-half
    const unsigned short* Ab = H + ((size_t)e * CAP + blockIdx.y * 128) * NF + ks * (NF / 2);
    const unsigned short* Bb = W2T + ((size_t)e * DM + nb * 128) * NF + ks * (NF / 2);
    f32x4 acc[4][4];
    gemm_core<NF / 2, NF>(Ab, Bb, As, Bs, acc);

    int tid = threadIdx.x, wave = tid >> 6, lane = tid & 63;
    int wr = (wave >> 1) * 64;
    int wc = (wave & 1) * 64;
    int slot0 = e * CAP + blockIdx.y * 128;
    int colbase = nb * 128 + wc + (lane & 15);
#pragma unroll
    for (int i = 0; i < 4; ++i) {
        int rbase = wr + i * 16 + (lane >> 4) * 4;
#pragma unroll
        for (int f = 0; f < 4; ++f) {
            int row = rbase + f;
            int t = slot_token[slot0 + row];
            if (t >= 0) {
                float g = gatev[t];
#pragma unroll
                for (int j = 0; j < 4; ++j) {
                    unsafeAtomicAdd(&out[(size_t)t * DM + colbase + j * 16], acc[i][j][f] * g);
                }
            }
        }
    }
}

extern "C" void kernel_launch(void* const* d_in, const int* in_sizes, int n_in,
                              void* d_out, int out_size, void* d_ws, size_t ws_size,
                              hipStream_t stream)
{
    const float* x  = (const float*)d_in[0];
    const float* wg = (const float*)d_in[1];
    const float* w1 = (const float*)d_in[2];
    const float* w2 = (const float*)d_in[3];
    float* out = (float*)d_out;

    char* ws = (char*)d_ws;
    size_t o = 0;
    auto nxt = [&](size_t b) { size_t r = o; o += (b + 255) & ~(size_t)255; return r; };
    int*   eid        = (int*)  (ws + nxt((size_t)NTOK * 4));
    float* gatev      = (float*)(ws + nxt((size_t)NTOK * 4));
    int*   slot_token = (int*)  (ws + nxt((size_t)NTOK * 4));
    unsigned short* Xd = (unsigned short*)(ws + nxt((size_t)NTOK * DM * 2));
    unsigned short* WT = (unsigned short*)(ws + nxt((size_t)NE * NF * DM * 2)); // W1T then W2T (aliased)
    unsigned short* Hb = (unsigned short*)(ws + nxt((size_t)NE * CAP * NF * 2));

    gate_kernel<<<NTOK / 4, 256, 0, stream>>>(x, wg, eid, gatev);
    scan_kernel<<<1, 1024, 0, stream>>>(eid, slot_token);
    convT_kernel<DM, NF><<<dim3(NF / 64, DM / 64, NE), 256, 0, stream>>>(w1, WT);
    gather_kernel<<<NTOK / 2, 256, 0, stream>>>(x, slot_token, Xd);
    gemm1_kernel<<<dim3(NF / 128, CAP / 128, NE), 256, 0, stream>>>(Xd, WT, Hb);
    convT_kernel<NF, DM><<<dim3(DM / 64, NF / 64, NE), 256, 0, stream>>>(w2, WT);
    hipMemsetAsync(d_out, 0, (size_t)out_size * sizeof(float), stream);
    gemm2_kernel<<<dim3((DM / 128) * 2, CAP / 128, NE), 256, 0, stream>>>(Hb, WT, slot_token, gatev, out);
}

// Round 5
// 555.100 us; speedup vs baseline: 1.0470x; 1.0154x over previous
//
#include <hip/hip_runtime.h>
#include <hip/hip_bf16.h>

// MoE top-1 (GShard) for MI355X.
// S=8192 tokens, m=1024, E=8, ffn=4096, C=1024.
// R7: 128x256 tile, 4 waves (2Mx2N), per-wave 64x128 = 4x8 acc. R2-R6 ledger:
//     no pipe saturated (MFMA 24%, LDS 50%, L2 22%) -> serialization-bound,
//     too little MFMA per fragment-load/barrier. Fatter acc: 32 MFMA/wave/step
//     vs 16 at unchanged fixed cost; LDS bytes/MFMA 0.5->0.375KB. Sync core
//     unchanged from R6 (single-barrier 2-phase, counted waits). Split-K x2 +
//     atomic epilogue kept on gemm2.

#define NTOK 8192
#define DM   1024
#define NE   8
#define NF   4096
#define CAP  1024

typedef __bf16 bf16x8 __attribute__((ext_vector_type(8)));
typedef float  f32x4  __attribute__((ext_vector_type(4)));
typedef unsigned short us8v __attribute__((ext_vector_type(8)));

__device__ __forceinline__ unsigned short f2bf(float f) {
    union { float f; unsigned int u; } v; v.f = f;
    unsigned int u = v.u;
    return (unsigned short)((u + 0x7FFFu + ((u >> 16) & 1u)) >> 16); // RNE
}

__device__ __forceinline__ void async_cp16(const unsigned short* g, unsigned short* l) {
    __builtin_amdgcn_global_load_lds(
        (const __attribute__((address_space(1))) void*)g,
        (__attribute__((address_space(3))) void*)l, 16, 0, 0);
}

// ---------------- gating: one wave per token ----------------
__global__ __launch_bounds__(256) void gate_kernel(
    const float* __restrict__ x, const float* __restrict__ wg,
    int* __restrict__ eid, float* __restrict__ gatev)
{
    int wave = threadIdx.x >> 6;
    int lane = threadIdx.x & 63;
    int t = blockIdx.x * 4 + wave;
    const float4* xr4 = (const float4*)(x + (size_t)t * DM);
    float acc[NE];
#pragma unroll
    for (int e = 0; e < NE; ++e) acc[e] = 0.f;
#pragma unroll
    for (int it = 0; it < 4; ++it) {
        int k4 = lane + it * 64;
        float4 xv = xr4[k4];
        float xc[4] = {xv.x, xv.y, xv.z, xv.w};
#pragma unroll
        for (int c = 0; c < 4; ++c) {
            const float4* wr = (const float4*)(wg + (size_t)(k4 * 4 + c) * NE);
            float4 w0 = wr[0], w1 = wr[1];
            acc[0] += xc[c] * w0.x; acc[1] += xc[c] * w0.y;
            acc[2] += xc[c] * w0.z; acc[3] += xc[c] * w0.w;
            acc[4] += xc[c] * w1.x; acc[5] += xc[c] * w1.y;
            acc[6] += xc[c] * w1.z; acc[7] += xc[c] * w1.w;
        }
    }
#pragma unroll
    for (int off = 32; off >= 1; off >>= 1) {
#pragma unroll
        for (int e = 0; e < NE; ++e) acc[e] += __shfl_xor(acc[e], off, 64);
    }
    if (lane == 0) {
        int best = 0; float bm = acc[0];
#pragma unroll
        for (int e = 1; e < NE; ++e) if (acc[e] > bm) { bm = acc[e]; best = e; } // first-max like jnp.argmax
        float ssum = 0.f;
#pragma unroll
        for (int e = 0; e < NE; ++e) ssum += __expf(acc[e] - bm);
        eid[t] = best;
        gatev[t] = 1.0f / ssum;  // softmax prob of argmax expert
    }
}

// ---------------- ordered per-expert cumsum, wave-shuffle scan ----------------
__global__ __launch_bounds__(1024) void scan_kernel(
    const int* __restrict__ eid, int* __restrict__ slot_token)
{
    __shared__ int wtot[16][NE];
    int tid = threadIdx.x;
    int lane = tid & 63, wv = tid >> 6;
#pragma unroll
    for (int i = 0; i < 8; ++i) slot_token[tid + i * 1024] = -1;

    int el[8];
    int cnt[NE];
#pragma unroll
    for (int e = 0; e < NE; ++e) cnt[e] = 0;
#pragma unroll
    for (int i = 0; i < 8; ++i) {
        int e = eid[tid * 8 + i];
        el[i] = e;
        cnt[e]++;
    }
    int incl[NE];
#pragma unroll
    for (int e = 0; e < NE; ++e) incl[e] = cnt[e];
#pragma unroll
    for (int off = 1; off <= 32; off <<= 1) {
#pragma unroll
        for (int e = 0; e < NE; ++e) {
            int v = __shfl_up(incl[e], off, 64);
            if (lane >= off) incl[e] += v;
        }
    }
    if (lane == 63) {
#pragma unroll
        for (int e = 0; e < NE; ++e) wtot[wv][e] = incl[e];
    }
    __syncthreads();
    int base[NE];
#pragma unroll
    for (int e = 0; e < NE; ++e) {
        int s = 0;
        for (int w = 0; w < 16; ++w) s += (w < wv) ? wtot[w][e] : 0;
        base[e] = s + incl[e] - cnt[e];   // exclusive prefix for this thread
    }
#pragma unroll
    for (int i = 0; i < 8; ++i) {
        int e = el[i];
        int loc = base[e]++;
        if (loc < CAP) slot_token[e * CAP + loc] = tid * 8 + i;
    }
}

// ---------------- f32 [E][K][N] -> bf16 [E][N][K] convert+transpose ----------------
template<int K, int N>
__global__ __launch_bounds__(256) void convT_kernel(
    const float* __restrict__ W, unsigned short* __restrict__ WT)
{
    __shared__ unsigned short tile[64][72];
    int e = blockIdx.z;
    int k0 = blockIdx.y * 64, n0 = blockIdx.x * 64;
    const float* Wp = W + (size_t)e * K * N;
    unsigned short* WTp = WT + (size_t)e * K * N;
    int tid = threadIdx.x;
    int cn = (tid & 15) * 4;
    int rk = tid >> 4;
#pragma unroll
    for (int i = 0; i < 4; ++i) {
        int k = rk + i * 16;
        float4 v = *(const float4*)(Wp + (size_t)(k0 + k) * N + n0 + cn);
        tile[cn + 0][k] = f2bf(v.x);
        tile[cn + 1][k] = f2bf(v.y);
        tile[cn + 2][k] = f2bf(v.z);
        tile[cn + 3][k] = f2bf(v.w);
    }
    __syncthreads();
    int ck = (tid & 7) * 8;
    int rn = tid >> 3;
#pragma unroll
    for (int i = 0; i < 2; ++i) {
        int n = rn + i * 32;
        us8v o;
#pragma unroll
        for (int c = 0; c < 8; ++c) o[c] = tile[n][ck + c];
        *(us8v*)(WTp + (size_t)(n0 + n) * K + k0 + ck) = o;
    }
}

// ---------------- gather dispatched tokens into bf16 [E*C][m] ----------------
__global__ __launch_bounds__(256) void gather_kernel(
    const float* __restrict__ x, const int* __restrict__ slot_token,
    unsigned short* __restrict__ Xd)
{
    int tid = threadIdx.x;
    int local = tid & 127;
    int slot = blockIdx.x * 2 + (tid >> 7);
    int t = slot_token[slot];
    int c = local * 8;
    us8v o;
    if (t >= 0) {
        const float4* p = (const float4*)(x + (size_t)t * DM + c);
        float4 v0 = p[0], v1 = p[1];
        o[0] = f2bf(v0.x); o[1] = f2bf(v0.y); o[2] = f2bf(v0.z); o[3] = f2bf(v0.w);
        o[4] = f2bf(v1.x); o[5] = f2bf(v1.y); o[6] = f2bf(v1.z); o[7] = f2bf(v1.w);
    } else {
#pragma unroll
        for (int c8 = 0; c8 < 8; ++c8) o[c8] = 0;
    }
    *(us8v*)(Xd + (size_t)slot * DM + c) = o;
}

// ---------------- bf16 GEMM core: 128x256 tile, BK=32, 2-phase single-barrier --
// 4 waves as 2Mx2N; per-wave 64x128 output, acc[4][8].
// As0: 2 buffers of 4096 shorts (128 rows x 32k). Bs0: 2 buffers of 8192 shorts
// (256 rows x 32k). Schedule per K-step (R6-verified):
//   STAGE(next) | ds_read(cur) | lgkmcnt(0)+sched_barrier | MFMA | vmcnt(0) | s_barrier
template<int KLEN, int LD>
__device__ __forceinline__ void gemm_core(
    const unsigned short* __restrict__ Ab, const unsigned short* __restrict__ Bb,
    unsigned short* As0, unsigned short* Bs0, f32x4 acc[4][8])
{
    int tid = threadIdx.x;
    int wave = tid >> 6, lane = tid & 63;
    int wr = (wave >> 1) * 64;        // M-half
    int wc = (wave & 1) * 128;        // N-half
#pragma unroll
    for (int i = 0; i < 4; ++i)
#pragma unroll
        for (int j = 0; j < 8; ++j) acc[i][j] = (f32x4){0.f, 0.f, 0.f, 0.f};

    int srow = (lane >> 2);
    int scol = (lane & 3) * 8;

    // prologue: stage tile 0 into buffer 0, drain, barrier
#pragma unroll
    for (int i = 0; i < 2; ++i) {
        int q = wave * 2 + i;                  // A: 8 chunks of 16 rows
        int row = q * 16 + srow;
        async_cp16(Ab + (size_t)row * LD + scol, As0 + q * 512);
    }
#pragma unroll
    for (int i = 0; i < 4; ++i) {
        int q = wave * 4 + i;                  // B: 16 chunks of 16 rows
        int row = q * 16 + srow;
        async_cp16(Bb + (size_t)row * LD + scol, Bs0 + q * 512);
    }
    asm volatile("s_waitcnt vmcnt(0)" ::: "memory");
    __builtin_amdgcn_s_barrier();

    int cur = 0;
    for (int kt = 0; kt < KLEN; kt += 32) {
        // phase A: issue next-tile stage first — it gets the read+MFMA window.
        if (kt + 32 < KLEN) {
            unsigned short* Asn = As0 + (cur ^ 1) * 4096;
            unsigned short* Bsn = Bs0 + (cur ^ 1) * 8192;
#pragma unroll
            for (int i = 0; i < 2; ++i) {
                int q = wave * 2 + i;
                int row = q * 16 + srow;
                async_cp16(Ab + (size_t)row * LD + kt + 32 + scol, Asn + q * 512);
            }
#pragma unroll
            for (int i = 0; i < 4; ++i) {
                int q = wave * 4 + i;
                int row = q * 16 + srow;
                async_cp16(Bb + (size_t)row * LD + kt + 32 + scol, Bsn + q * 512);
            }
        }
        // phase B: ds_read current-tile fragments
        const unsigned short* Asc = As0 + cur * 4096;
        const unsigned short* Bsc = Bs0 + cur * 8192;
        bf16x8 af[4], bfr[8];
#pragma unroll
        for (int i = 0; i < 4; ++i) {
            int r = wr + i * 16 + (lane & 15);
            af[i] = *(const bf16x8*)(Asc + r * 32 + (lane >> 4) * 8);
        }
#pragma unroll
        for (int j = 0; j < 8; ++j) {
            int c = wc + j * 16 + (lane & 15);
            bfr[j] = *(const bf16x8*)(Bsc + c * 32 + (lane >> 4) * 8);
        }
        asm volatile("s_waitcnt lgkmcnt(0)" ::: "memory");
        __builtin_amdgcn_sched_barrier(0);
        // phase C: MFMA cluster (32 per wave)
#pragma unroll
        for (int i = 0; i < 4; ++i)
#pragma unroll
            for (int j = 0; j < 8; ++j)
                acc[i][j] = __builtin_amdgcn_mfma_f32_16x16x32_bf16(af[i], bfr[j], acc[i][j], 0, 0, 0);
        // phase D: one barrier per K-step, staged tile drained just before it.
        __builtin_amdgcn_sched_barrier(0);
        asm volatile("s_waitcnt vmcnt(0)" ::: "memory");
        __builtin_amdgcn_s_barrier();
        cur ^= 1;
    }
}

// GEMM1: H[e] = relu(Xd[e] @ W1[e]) -> bf16, LDS-transpose epilogue w/ 16B stores.
__global__ __launch_bounds__(256, 2) void gemm1_kernel(
    const unsigned short* __restrict__ Xd, const unsigned short* __restrict__ W1T,
    unsigned short* __restrict__ H)
{
    __shared__ unsigned short smem[24576];  // As dbuf(8192) + Bs dbuf(16384) = 48KB
    unsigned short* As = smem;
    unsigned short* Bs = smem + 8192;
    int e = blockIdx.z;
    const unsigned short* Ab = Xd + ((size_t)e * CAP + blockIdx.y * 128) * DM;
    const unsigned short* Bb = W1T + ((size_t)e * NF + blockIdx.x * 256) * DM;
    f32x4 acc[4][8];
    gemm_core<DM, DM>(Ab, Bb, As, Bs, acc);
    // gemm_core ends with lgkmcnt(0)+s_barrier: all LDS reads done, safe to reuse.

    int tid = threadIdx.x, wave = tid >> 6, lane = tid & 63;
    int wc = (wave & 1) * 128;
    size_t Hrow0 = ((size_t)e * CAP + blockIdx.y * 128) * NF + blockIdx.x * 256;
    unsigned short* buf = smem;  // 64 rows x 256 cols bf16 = 32KB
#pragma unroll
    for (int p = 0; p < 2; ++p) {
        if ((wave >> 1) == p) {  // both col-half waves of this row-half fill
#pragma unroll
            for (int i = 0; i < 4; ++i) {
#pragma unroll
                for (int j = 0; j < 8; ++j) {
                    int col = wc + j * 16 + (lane & 15);
#pragma unroll
                    for (int f = 0; f < 4; ++f) {
                        int lr = i * 16 + (lane >> 4) * 4 + f;
                        float v = acc[i][j][f];
                        v = v > 0.f ? v : 0.f;
                        buf[lr * 256 + col] = f2bf(v);
                    }
                }
            }
        }
        __syncthreads();
#pragma unroll
        for (int v = 0; v < 8; ++v) {
            int sidx = tid + v * 256;
            int r = sidx >> 5, seg = sidx & 31;
            us8v o = *(const us8v*)(buf + r * 256 + seg * 8);
            *(us8v*)(H + Hrow0 + (size_t)(p * 64 + r) * NF + seg * 8) = o;
        }
        __syncthreads();
    }
}

// GEMM2: EO[e] = H[e] @ W2[e]; 128x256 2-phase core, split-K x2,
// gate-scale + scatter via HW f32 atomics (2 commutative adds -> deterministic).
__global__ __launch_bounds__(256, 2) void gemm2_kernel(
    const unsigned short* __restrict__ H, const unsigned short* __restrict__ W2T,
    const int* __restrict__ slot_token, const float* __restrict__ gatev,
    float* __restrict__ out)
{
    __shared__ unsigned short smem[24576];  // As dbuf + Bs dbuf = 48KB
    unsigned short* As = smem;
    unsigned short* Bs = smem + 8192;
    int e = blockIdx.z;
    int nb = blockIdx.x >> 1;       // n-tile (DM/256 = 4)
    int ks = blockIdx.x & 1;        // k-half
    const unsigned short* Ab = H + ((size_t)e * CAP + blockIdx.y * 128) * NF + ks * (NF / 2);
    const unsigned short* Bb = W2T + ((size_t)e * DM + nb * 256) * NF + ks * (NF / 2);
    f32x4 acc[4][8];
    gemm_core<NF / 2, NF>(Ab, Bb, As, Bs, acc);

    int tid = threadIdx.x, wave = tid >> 6, lane = tid & 63;
    int wr = (wave >> 1) * 64;
    int wc = (wave & 1) * 128;
    int slot0 = e * CAP + blockIdx.y * 128;
    int colbase = nb * 256 + wc + (lane & 15);
#pragma unroll
    for (int i = 0; i < 4; ++i) {
        int rbase = wr + i * 16 + (lane >> 4) * 4;
#pragma unroll
        for (int f = 0; f < 4; ++f) {
            int row = rbase + f;
            int t = slot_token[slot0 + row];
            if (t >= 0) {
                float g = gatev[t];
#pragma unroll
                for (int j = 0; j < 8; ++j) {
                    unsafeAtomicAdd(&out[(size_t)t * DM + colbase + j * 16], acc[i][j][f] * g);
                }
            }
        }
    }
}

extern "C" void kernel_launch(void* const* d_in, const int* in_sizes, int n_in,
                              void* d_out, int out_size, void* d_ws, size_t ws_size,
                              hipStream_t stream)
{
    const float* x  = (const float*)d_in[0];
    const float* wg = (const float*)d_in[1];
    const float* w1 = (const float*)d_in[2];
    const float* w2 = (const float*)d_in[3];
    float* out = (float*)d_out;

    char* ws = (char*)d_ws;
    size_t o = 0;
    auto nxt = [&](size_t b) { size_t r = o; o += (b + 255) & ~(size_t)255; return r; };
    int*   eid        = (int*)  (ws + nxt((size_t)NTOK * 4));
    float* gatev      = (float*)(ws + nxt((size_t)NTOK * 4));
    int*   slot_token = (int*)  (ws + nxt((size_t)NTOK * 4));
    unsigned short* Xd = (unsigned short*)(ws + nxt((size_t)NTOK * DM * 2));
    unsigned short* WT = (unsigned short*)(ws + nxt((size_t)NE * NF * DM * 2)); // W1T then W2T (aliased)
    unsigned short* Hb = (unsigned short*)(ws + nxt((size_t)NE * CAP * NF * 2));

    gate_kernel<<<NTOK / 4, 256, 0, stream>>>(x, wg, eid, gatev);
    scan_kernel<<<1, 1024, 0, stream>>>(eid, slot_token);
    convT_kernel<DM, NF><<<dim3(NF / 64, DM / 64, NE), 256, 0, stream>>>(w1, WT);
    gather_kernel<<<NTOK / 2, 256, 0, stream>>>(x, slot_token, Xd);
    gemm1_kernel<<<dim3(NF / 256, CAP / 128, NE), 256, 0, stream>>>(Xd, WT, Hb);
    convT_kernel<NF, DM><<<dim3(DM / 64, NF / 64, NE), 256, 0, stream>>>(w2, WT);
    hipMemsetAsync(d_out, 0, (size_t)out_size * sizeof(float), stream);
    gemm2_kernel<<<dim3((DM / 256) * 2, CAP / 128, NE), 256, 0, stream>>>(Hb, WT, slot_token, gatev, out);
}

// Round 6
// 533.517 us; speedup vs baseline: 1.0894x; 1.0405x over previous
//
#include <hip/hip_runtime.h>
#include <hip/hip_bf16.h>

// MoE top-1 (GShard) for MI355X.
// S=8192 tokens, m=1024, E=8, ffn=4096, C=1024.
// R8: 256x256/BK=64 8-wave core, 128KB LDS dbuf, counted-vmcnt pipeline
//     (vmcnt(8), never 0 in main loop; prefetch depth = 1 full iteration),
//     T2 st-swizzle byte^=(row&7)<<4 on BOTH sides (pre-swizzled global src,
//     swizzled ds_read), T1 XCD-chunk block swizzle. 128 MFMA/wave between
//     barriers. R2-R7: every 2-phase variant pinned at MfmaUtil~20 (m233:
//     2ph critical path is 72% stage+sync) -> T3+T4 is the cataloged escape.

#define NTOK 8192
#define DM   1024
#define NE   8
#define NF   4096
#define CAP  1024

typedef __bf16 bf16x8 __attribute__((ext_vector_type(8)));
typedef float  f32x4  __attribute__((ext_vector_type(4)));
typedef unsigned short us8v __attribute__((ext_vector_type(8)));

__device__ __forceinline__ unsigned short f2bf(float f) {
    union { float f; unsigned int u; } v; v.f = f;
    unsigned int u = v.u;
    return (unsigned short)((u + 0x7FFFu + ((u >> 16) & 1u)) >> 16); // RNE
}

__device__ __forceinline__ void async_cp16(const unsigned short* g, unsigned short* l) {
    __builtin_amdgcn_global_load_lds(
        (const __attribute__((address_space(1))) void*)g,
        (__attribute__((address_space(3))) void*)l, 16, 0, 0);
}

// ---------------- gating: one wave per token ----------------
__global__ __launch_bounds__(256) void gate_kernel(
    const float* __restrict__ x, const float* __restrict__ wg,
    int* __restrict__ eid, float* __restrict__ gatev)
{
    int wave = threadIdx.x >> 6;
    int lane = threadIdx.x & 63;
    int t = blockIdx.x * 4 + wave;
    const float4* xr4 = (const float4*)(x + (size_t)t * DM);
    float acc[NE];
#pragma unroll
    for (int e = 0; e < NE; ++e) acc[e] = 0.f;
#pragma unroll
    for (int it = 0; it < 4; ++it) {
        int k4 = lane + it * 64;
        float4 xv = xr4[k4];
        float xc[4] = {xv.x, xv.y, xv.z, xv.w};
#pragma unroll
        for (int c = 0; c < 4; ++c) {
            const float4* wr = (const float4*)(wg + (size_t)(k4 * 4 + c) * NE);
            float4 w0 = wr[0], w1 = wr[1];
            acc[0] += xc[c] * w0.x; acc[1] += xc[c] * w0.y;
            acc[2] += xc[c] * w0.z; acc[3] += xc[c] * w0.w;
            acc[4] += xc[c] * w1.x; acc[5] += xc[c] * w1.y;
            acc[6] += xc[c] * w1.z; acc[7] += xc[c] * w1.w;
        }
    }
#pragma unroll
    for (int off = 32; off >= 1; off >>= 1) {
#pragma unroll
        for (int e = 0; e < NE; ++e) acc[e] += __shfl_xor(acc[e], off, 64);
    }
    if (lane == 0) {
        int best = 0; float bm = acc[0];
#pragma unroll
        for (int e = 1; e < NE; ++e) if (acc[e] > bm) { bm = acc[e]; best = e; } // first-max like jnp.argmax
        float ssum = 0.f;
#pragma unroll
        for (int e = 0; e < NE; ++e) ssum += __expf(acc[e] - bm);
        eid[t] = best;
        gatev[t] = 1.0f / ssum;  // softmax prob of argmax expert
    }
}

// ---------------- ordered per-expert cumsum, wave-shuffle scan ----------------
__global__ __launch_bounds__(1024) void scan_kernel(
    const int* __restrict__ eid, int* __restrict__ slot_token)
{
    __shared__ int wtot[16][NE];
    int tid = threadIdx.x;
    int lane = tid & 63, wv = tid >> 6;
#pragma unroll
    for (int i = 0; i < 8; ++i) slot_token[tid + i * 1024] = -1;

    int el[8];
    int cnt[NE];
#pragma unroll
    for (int e = 0; e < NE; ++e) cnt[e] = 0;
#pragma unroll
    for (int i = 0; i < 8; ++i) {
        int e = eid[tid * 8 + i];
        el[i] = e;
        cnt[e]++;
    }
    int incl[NE];
#pragma unroll
    for (int e = 0; e < NE; ++e) incl[e] = cnt[e];
#pragma unroll
    for (int off = 1; off <= 32; off <<= 1) {
#pragma unroll
        for (int e = 0; e < NE; ++e) {
            int v = __shfl_up(incl[e], off, 64);
            if (lane >= off) incl[e] += v;
        }
    }
    if (lane == 63) {
#pragma unroll
        for (int e = 0; e < NE; ++e) wtot[wv][e] = incl[e];
    }
    __syncthreads();
    int base[NE];
#pragma unroll
    for (int e = 0; e < NE; ++e) {
        int s = 0;
        for (int w = 0; w < 16; ++w) s += (w < wv) ? wtot[w][e] : 0;
        base[e] = s + incl[e] - cnt[e];   // exclusive prefix for this thread
    }
#pragma unroll
    for (int i = 0; i < 8; ++i) {
        int e = el[i];
        int loc = base[e]++;
        if (loc < CAP) slot_token[e * CAP + loc] = tid * 8 + i;
    }
}

// ---------------- f32 [E][K][N] -> bf16 [E][N][K] convert+transpose ----------------
template<int K, int N>
__global__ __launch_bounds__(256) void convT_kernel(
    const float* __restrict__ W, unsigned short* __restrict__ WT)
{
    __shared__ unsigned short tile[64][72];
    int e = blockIdx.z;
    int k0 = blockIdx.y * 64, n0 = blockIdx.x * 64;
    const float* Wp = W + (size_t)e * K * N;
    unsigned short* WTp = WT + (size_t)e * K * N;
    int tid = threadIdx.x;
    int cn = (tid & 15) * 4;
    int rk = tid >> 4;
#pragma unroll
    for (int i = 0; i < 4; ++i) {
        int k = rk + i * 16;
        float4 v = *(const float4*)(Wp + (size_t)(k0 + k) * N + n0 + cn);
        tile[cn + 0][k] = f2bf(v.x);
        tile[cn + 1][k] = f2bf(v.y);
        tile[cn + 2][k] = f2bf(v.z);
        tile[cn + 3][k] = f2bf(v.w);
    }
    __syncthreads();
    int ck = (tid & 7) * 8;
    int rn = tid >> 3;
#pragma unroll
    for (int i = 0; i < 2; ++i) {
        int n = rn + i * 32;
        us8v o;
#pragma unroll
        for (int c = 0; c < 8; ++c) o[c] = tile[n][ck + c];
        *(us8v*)(WTp + (size_t)(n0 + n) * K + k0 + ck) = o;
    }
}

// ---------------- gather dispatched tokens into bf16 [E*C][m] ----------------
__global__ __launch_bounds__(256) void gather_kernel(
    const float* __restrict__ x, const int* __restrict__ slot_token,
    unsigned short* __restrict__ Xd)
{
    int tid = threadIdx.x;
    int local = tid & 127;
    int slot = blockIdx.x * 2 + (tid >> 7);
    int t = slot_token[slot];
    int c = local * 8;
    us8v o;
    if (t >= 0) {
        const float4* p = (const float4*)(x + (size_t)t * DM + c);
        float4 v0 = p[0], v1 = p[1];
        o[0] = f2bf(v0.x); o[1] = f2bf(v0.y); o[2] = f2bf(v0.z); o[3] = f2bf(v0.w);
        o[4] = f2bf(v1.x); o[5] = f2bf(v1.y); o[6] = f2bf(v1.z); o[7] = f2bf(v1.w);
    } else {
#pragma unroll
        for (int c8 = 0; c8 < 8; ++c8) o[c8] = 0;
    }
    *(us8v*)(Xd + (size_t)slot * DM + c) = o;
}

// ======== 256x256 / BK=64 / 8-wave counted-vmcnt core, T2-swizzled LDS ========
// LDS (shorts): A[2][16384] at 0, B[2][16384] at 32768. 128 KiB total.
// Swizzle (bytes within a 128B row): b ^= (row&7)<<4. Staged via inverse-
// swizzled GLOBAL source + linear LDS dest (rule #21); read with same XOR.
// Pipeline: at top of iter t, buf[cur] holds tile t; tile t+1's 8 loads/thread
// are in flight. After compute: barrier; STAGE(t+2 -> cur); vmcnt(8) (= t+1
// landed, t+2 still flying); barrier. vmcnt never drains to 0 mid-loop.
template<int KLEN, int LD>
__device__ __forceinline__ void gemm_core256(
    const unsigned short* __restrict__ Ab, const unsigned short* __restrict__ Bb,
    unsigned short* sm, f32x4 acc[8][4])
{
    int tid = threadIdx.x;              // 0..511
    int wave = tid >> 6, lane = tid & 63;
    int wr = (wave >> 2) * 128;         // M-half
    int wc = (wave & 3) * 64;           // N-quarter
#pragma unroll
    for (int i = 0; i < 8; ++i)
#pragma unroll
        for (int j = 0; j < 4; ++j) acc[i][j] = (f32x4){0.f, 0.f, 0.f, 0.f};

    int g_row = tid >> 3;               // +s*64; row within 256-row panel
    int g_colb = (tid & 7) * 16;        // byte col within 128B row

    constexpr int NT = KLEN / 64;

#define STAGE_TILE(T, BUF)                                                      \
    {                                                                           \
        int kt_ = (T) * 64;                                                     \
        unsigned short* Ad_ = sm + (BUF) * 16384;                               \
        unsigned short* Bd_ = sm + 32768 + (BUF) * 16384;                       \
        _Pragma("unroll")                                                       \
        for (int s_ = 0; s_ < 4; ++s_) {                                        \
            int row_ = s_ * 64 + g_row;                                         \
            int sc_ = (g_colb ^ ((row_ & 7) << 4)) >> 1;                        \
            async_cp16(Ab + (size_t)row_ * LD + kt_ + sc_, Ad_ + s_ * 4096 + tid * 8); \
        }                                                                       \
        _Pragma("unroll")                                                       \
        for (int s_ = 0; s_ < 4; ++s_) {                                        \
            int row_ = s_ * 64 + g_row;                                         \
            int sc_ = (g_colb ^ ((row_ & 7) << 4)) >> 1;                        \
            async_cp16(Bb + (size_t)row_ * LD + kt_ + sc_, Bd_ + s_ * 4096 + tid * 8); \
        }                                                                       \
    }

    // prologue: tiles 0 and 1 in flight; wait only for tile 0 (vmcnt 8 = tile1's)
    STAGE_TILE(0, 0)
    STAGE_TILE(1, 1)
    asm volatile("s_waitcnt vmcnt(8)" ::: "memory");
    __builtin_amdgcn_s_barrier();

    int cur = 0;
    for (int t = 0; t < NT; ++t) {
        const unsigned short* Ac = sm + cur * 16384;
        const unsigned short* Bc = sm + 32768 + cur * 16384;
#pragma unroll
        for (int ks = 0; ks < 2; ++ks) {
            // swizzled k-offset (shorts) for this lane's fragment
            int xo = ((ks * 64 + ((lane >> 4) * 16)) ^ ((lane & 7) << 4)) >> 1;
            bf16x8 af[8], bfr[4];
#pragma unroll
            for (int i = 0; i < 8; ++i) {
                int r = wr + i * 16 + (lane & 15);
                af[i] = *(const bf16x8*)(Ac + r * 64 + xo);
            }
#pragma unroll
            for (int j = 0; j < 4; ++j) {
                int c = wc + j * 16 + (lane & 15);
                bfr[j] = *(const bf16x8*)(Bc + c * 64 + xo);
            }
            asm volatile("s_waitcnt lgkmcnt(0)" ::: "memory");
            __builtin_amdgcn_sched_barrier(0);
#pragma unroll
            for (int i = 0; i < 8; ++i)
#pragma unroll
                for (int j = 0; j < 4; ++j)
                    acc[i][j] = __builtin_amdgcn_mfma_f32_16x16x32_bf16(af[i], bfr[j], acc[i][j], 0, 0, 0);
        }
        __builtin_amdgcn_s_barrier();   // all waves done reading buf[cur]
        if (t + 2 < NT) {
            STAGE_TILE(t + 2, cur)      // restage freed buffer
            asm volatile("s_waitcnt vmcnt(8)" ::: "memory");  // tile t+1 landed
        } else if (t + 1 < NT) {
            asm volatile("s_waitcnt vmcnt(0)" ::: "memory");  // tail drain (once)
        }
        __builtin_amdgcn_s_barrier();   // publish buf[cur^1]
        cur ^= 1;
    }
#undef STAGE_TILE
}

// GEMM1: H[e] = relu(Xd[e] @ W1[e]) -> bf16. 1-D grid, XCD-chunk swizzle.
__global__ __launch_bounds__(512, 1) void gemm1_kernel(
    const unsigned short* __restrict__ Xd, const unsigned short* __restrict__ W1T,
    unsigned short* __restrict__ H)
{
    __shared__ unsigned short sm[65536];   // 128 KiB
    // grid = 512 = (NF/256=16) x (CAP/256=4) x NE; XCD swizzle: chunk of 64 = one expert slice
    int vid = ((int)blockIdx.x & 7) * 64 + ((int)blockIdx.x >> 3);
    int xb = vid & 15, yb = (vid >> 4) & 3, e = vid >> 6;
    const unsigned short* Ab = Xd + ((size_t)e * CAP + yb * 256) * DM;
    const unsigned short* Bb = W1T + ((size_t)e * NF + xb * 256) * DM;
    f32x4 acc[8][4];
    gemm_core256<DM, DM>(Ab, Bb, sm, acc);
    // core ends: lgkm drained per-wave before its last barrier; LDS reusable.
    __builtin_amdgcn_s_barrier();

    int tid = threadIdx.x, wave = tid >> 6, lane = tid & 63;
    int wc = (wave & 3) * 64;
    size_t Hrow0 = ((size_t)e * CAP + yb * 256) * NF + xb * 256;
    unsigned short* buf = sm;   // 128 rows x 264 cols (padded) = 67.6KB
#pragma unroll
    for (int p = 0; p < 2; ++p) {
        if ((wave >> 2) == p) {
#pragma unroll
            for (int i = 0; i < 8; ++i) {
#pragma unroll
                for (int j = 0; j < 4; ++j) {
                    int col = wc + j * 16 + (lane & 15);
#pragma unroll
                    for (int f = 0; f < 4; ++f) {
                        int lr = i * 16 + (lane >> 4) * 4 + f;
                        float v = acc[i][j][f];
                        v = v > 0.f ? v : 0.f;
                        buf[lr * 264 + col] = f2bf(v);
                    }
                }
            }
        }
        __syncthreads();
#pragma unroll
        for (int v = 0; v < 8; ++v) {
            int sidx = tid + v * 512;
            int r = sidx >> 5, seg = sidx & 31;
            us8v o = *(const us8v*)(buf + r * 264 + seg * 8);
            *(us8v*)(H + Hrow0 + (size_t)(p * 128 + r) * NF + seg * 8) = o;
        }
        __syncthreads();
    }
}

// GEMM2: EO[e] = H[e] @ W2[e]; split-K x2; gate-scale + atomic scatter.
__global__ __launch_bounds__(512, 1) void gemm2_kernel(
    const unsigned short* __restrict__ H, const unsigned short* __restrict__ W2T,
    const int* __restrict__ slot_token, const float* __restrict__ gatev,
    float* __restrict__ out)
{
    __shared__ unsigned short sm[65536];   // 128 KiB
    // grid = 256 = (nb=4) x (ks=2) x (yb=4) x NE; chunk of 32 = one expert slice
    int vid = ((int)blockIdx.x & 7) * 32 + ((int)blockIdx.x >> 3);
    int nb = vid & 3, ks = (vid >> 2) & 1, yb = (vid >> 3) & 3, e = vid >> 5;
    const unsigned short* Ab = H + ((size_t)e * CAP + yb * 256) * NF + ks * (NF / 2);
    const unsigned short* Bb = W2T + ((size_t)e * DM + nb * 256) * NF + ks * (NF / 2);
    f32x4 acc[8][4];
    gemm_core256<NF / 2, NF>(Ab, Bb, sm, acc);

    int tid = threadIdx.x, wave = tid >> 6, lane = tid & 63;
    int wr = (wave >> 2) * 128;
    int wc = (wave & 3) * 64;
    int slot0 = e * CAP + yb * 256;
    int colbase = nb * 256 + wc + (lane & 15);
#pragma unroll
    for (int i = 0; i < 8; ++i) {
        int rbase = wr + i * 16 + (lane >> 4) * 4;
#pragma unroll
        for (int f = 0; f < 4; ++f) {
            int row = rbase + f;
            int t = slot_token[slot0 + row];
            if (t >= 0) {
                float g = gatev[t];
#pragma unroll
                for (int j = 0; j < 4; ++j) {
                    unsafeAtomicAdd(&out[(size_t)t * DM + colbase + j * 16], acc[i][j][f] * g);
                }
            }
        }
    }
}

extern "C" void kernel_launch(void* const* d_in, const int* in_sizes, int n_in,
                              void* d_out, int out_size, void* d_ws, size_t ws_size,
                              hipStream_t stream)
{
    const float* x  = (const float*)d_in[0];
    const float* wg = (const float*)d_in[1];
    const float* w1 = (const float*)d_in[2];
    const float* w2 = (const float*)d_in[3];
    float* out = (float*)d_out;

    char* ws = (char*)d_ws;
    size_t o = 0;
    auto nxt = [&](size_t b) { size_t r = o; o += (b + 255) & ~(size_t)255; return r; };
    int*   eid        = (int*)  (ws + nxt((size_t)NTOK * 4));
    float* gatev      = (float*)(ws + nxt((size_t)NTOK * 4));
    int*   slot_token = (int*)  (ws + nxt((size_t)NTOK * 4));
    unsigned short* Xd = (unsigned short*)(ws + nxt((size_t)NTOK * DM * 2));
    unsigned short* WT = (unsigned short*)(ws + nxt((size_t)NE * NF * DM * 2)); // W1T then W2T (aliased)
    unsigned short* Hb = (unsigned short*)(ws + nxt((size_t)NE * CAP * NF * 2));

    gate_kernel<<<NTOK / 4, 256, 0, stream>>>(x, wg, eid, gatev);
    scan_kernel<<<1, 1024, 0, stream>>>(eid, slot_token);
    convT_kernel<DM, NF><<<dim3(NF / 64, DM / 64, NE), 256, 0, stream>>>(w1, WT);
    gather_kernel<<<NTOK / 2, 256, 0, stream>>>(x, slot_token, Xd);
    gemm1_kernel<<<dim3(512), 512, 0, stream>>>(Xd, WT, Hb);
    convT_kernel<NF, DM><<<dim3(DM / 64, NF / 64, NE), 256, 0, stream>>>(w2, WT);
    hipMemsetAsync(d_out, 0, (size_t)out_size * sizeof(float), stream);
    gemm2_kernel<<<dim3(256), 512, 0, stream>>>(Hb, WT, slot_token, gatev, out);
}